// Round 15
// baseline (382.773 us; speedup 1.0000x reference)
//
#include <hip/hip_runtime.h>
#include <math.h>

// Problem: B=4, S=2048, D=1024, H=16, DK=64.
// out = softmax((q Wq^T)(k Wk^T)^T / 8) (v Wv^T) Wo^T, heads split on D.
//
// Pipeline:
//   1. cast_all: fp32->bf16 for {q,k,v,Wq,Wk,Wv,Wo} in ONE launch
//   2. gemm_qkv: Qp=(q@Wq^T)*(0.125*log2e), Kp=k@Wk^T (bf16 [8192,1024]),
//                VpT = (v@Wv^T) stored transposed [B*1024, 2048] bf16
//   3. attn: flash attention, S^T/O^T, QBLK=256, R12 mi-dovetail schedule.
//            R13: 2-tile unroll — stage tiles (t+2,t+3) into the other
//            buffer PAIR, compute 2 resident tiles, ONE barrier per 2 tiles
//            (16+1 barriers vs 32+1). Occupancy is grid-capped at 2
//            blocks/CU (512 blocks), so LDS 80KB costs nothing.
//   4. gemm_out: out = Xp @ Wo^T (fp32), BK=64 + C^T epilogue -> float4.

#define DEV __device__ __forceinline__

typedef __bf16 bf16x8 __attribute__((ext_vector_type(8)));
typedef __bf16 bf16x2 __attribute__((ext_vector_type(2)));
typedef float f32x4 __attribute__((ext_vector_type(4)));
typedef unsigned int u32x2 __attribute__((ext_vector_type(2)));

typedef __attribute__((address_space(1))) const unsigned int g_u32;
typedef __attribute__((address_space(3))) unsigned int l_u32;

DEV unsigned short f2bf(float x) {  // RNE truncate to bf16
  unsigned int u = __float_as_uint(x);
  u += 0x7fffu + ((u >> 16) & 1u);
  return (unsigned short)(u >> 16);
}

DEV unsigned int pack2bf(float a, float b) {
#if __has_builtin(__builtin_amdgcn_cvt_pk_bf16_f32)
  bf16x2 r = __builtin_amdgcn_cvt_pk_bf16_f32(a, b);
  union { bf16x2 v; unsigned int u; } c;
  c.v = r;
  return c.u;
#else
  unsigned int ua = __float_as_uint(a) + 0x8000u;
  unsigned int ub = __float_as_uint(b) + 0x8000u;
  return (ua >> 16) | (ub & 0xffff0000u);
#endif
}

DEV float fexp2(float x) {
#if __has_builtin(__builtin_amdgcn_exp2f)
  return __builtin_amdgcn_exp2f(x);
#else
  return __expf(x * 0.69314718056f);
#endif
}

DEV void ld16(const unsigned short* g, unsigned short* l) {
  // async global->LDS, 16B per lane; LDS dest = wave-uniform base + lane*16
  __builtin_amdgcn_global_load_lds((g_u32*)g, (l_u32*)l, 16, 0, 0);
}

// One launch for all 7 casts. Blocks 0..24575: q,k,v (8192 blocks each,
// 2M float4 per tensor). Blocks 24576..28671: weights (1024 blocks each).
__global__ __launch_bounds__(256) void cast_all(
    const float* __restrict__ q, const float* __restrict__ k,
    const float* __restrict__ v, const float* __restrict__ w0,
    const float* __restrict__ w1, const float* __restrict__ w2,
    const float* __restrict__ w3, unsigned short* __restrict__ qb,
    unsigned short* __restrict__ kb, unsigned short* __restrict__ vb,
    unsigned short* __restrict__ o0, unsigned short* __restrict__ o1,
    unsigned short* __restrict__ o2, unsigned short* __restrict__ o3) {
  const int bb = blockIdx.x;
  const float* src;
  unsigned short* dst;
  int i;
  if (bb < 24576) {
    const int z = bb >> 13, lb = bb & 8191;
    src = (z == 0) ? q : (z == 1) ? k : v;
    dst = (z == 0) ? qb : (z == 1) ? kb : vb;
    i = lb * 256 + threadIdx.x;
  } else {
    const int t = bb - 24576;
    const int z = t >> 10, lb = t & 1023;
    src = (z == 0) ? w0 : (z == 1) ? w1 : (z == 2) ? w2 : w3;
    dst = (z == 0) ? o0 : (z == 1) ? o1 : (z == 2) ? o2 : o3;
    i = lb * 256 + threadIdx.x;
  }
  float4 vv = reinterpret_cast<const float4*>(src)[i];
  ushort4 o;
  o.x = f2bf(vv.x); o.y = f2bf(vv.y); o.z = f2bf(vv.z); o.w = f2bf(vv.w);
  reinterpret_cast<ushort4*>(dst)[i] = o;
}

// ---- NT GEMM core, BK=64: C[128x128] tile, A [M,1024] bf16 rm, W [N,1024].
// 4 waves, each 64x64 (4x4 MFMA tiles of 16x16x32 bf16). 32 MFMA per barrier
// pair. LDS tiles 128x64 (row stride 128B) with XOR granule swizzle
// (phys_granule = logical ^ (row&7)) -> conflict-free b128 reads.
// SW=true computes C^T (mfma(bF,aF)) -> acc[j][i], lane holds 4 consecutive
// output cols of one row; SW=false computes C -> acc[i][j] (m97 layout).
template <bool SW>
DEV void gemm_core(const unsigned short* __restrict__ A,
                   const unsigned short* __restrict__ W,
                   unsigned short* As, unsigned short* Bs,
                   f32x4 (&acc)[4][4], int tileM, int tileN) {
  const int tid = threadIdx.x;
  const int w = tid >> 6, lane = tid & 63;
  const int wr = (w & 1) * 64, wc = (w >> 1) * 64;
  const int l15 = lane & 15, g4 = lane >> 4, l7 = l15 & 7;
  const int rsub = lane >> 3;            // row within 8-row staging chunk
  const int gsrc = (lane & 7) ^ rsub;    // swizzled source granule (8 shorts)

  const f32x4 fzero = {0.f, 0.f, 0.f, 0.f};
#pragma unroll
  for (int i = 0; i < 4; i++)
#pragma unroll
    for (int j = 0; j < 4; j++) acc[i][j] = fzero;

  for (int k0 = 0; k0 < 1024; k0 += 64) {
#pragma unroll
    for (int j = 0; j < 4; ++j) {
      const int c = w * 4 + j;  // chunk: 8 rows x 128B = 1KB
      ld16(A + (size_t)(tileM + c * 8 + rsub) * 1024 + k0 + gsrc * 8, As + c * 512);
      ld16(W + (size_t)(tileN + c * 8 + rsub) * 1024 + k0 + gsrc * 8, Bs + c * 512);
    }
    __syncthreads();
#pragma unroll
    for (int kc = 0; kc < 2; kc++) {
      const int ph = ((kc * 4 + g4) ^ l7) * 8;
      bf16x8 aF[4], bF[4];
#pragma unroll
      for (int i = 0; i < 4; i++)
        aF[i] = *reinterpret_cast<const bf16x8*>(&As[(wr + i * 16 + l15) * 64 + ph]);
#pragma unroll
      for (int j = 0; j < 4; j++)
        bF[j] = *reinterpret_cast<const bf16x8*>(&Bs[(wc + j * 16 + l15) * 64 + ph]);
#pragma unroll
      for (int i = 0; i < 4; i++)
#pragma unroll
        for (int j = 0; j < 4; j++) {
          if (SW)
            acc[j][i] = __builtin_amdgcn_mfma_f32_16x16x32_bf16(bF[j], aF[i], acc[j][i], 0, 0, 0);
          else
            acc[i][j] = __builtin_amdgcn_mfma_f32_16x16x32_bf16(aF[i], bF[j], acc[i][j], 0, 0, 0);
        }
    }
    __syncthreads();
  }
}

__global__ __launch_bounds__(256) void gemm_qkv(
    const unsigned short* __restrict__ qb, const unsigned short* __restrict__ kb,
    const unsigned short* __restrict__ vb, const unsigned short* __restrict__ Wq,
    const unsigned short* __restrict__ Wk, const unsigned short* __restrict__ Wv,
    unsigned short* __restrict__ Qp, unsigned short* __restrict__ Kp,
    unsigned short* __restrict__ VpT) {
  __shared__ __align__(16) unsigned short As[128 * 64];
  __shared__ __align__(16) unsigned short Bs[128 * 64];
  const int z = blockIdx.z;
  const int tileM = blockIdx.x * 128, tileN = blockIdx.y * 128;
  const int tid = threadIdx.x, w = tid >> 6, lane = tid & 63;
  const int wr = (w & 1) * 64, wc = (w >> 1) * 64;
  const int l15 = lane & 15, g4 = lane >> 4;
  f32x4 acc[4][4];

  if (z < 2) {
    // C^T core: lane holds row tileM+wr+i*16+l15, cols +wc+j*16+g4*4+(0..3)
    gemm_core<true>((z == 0) ? qb : kb, (z == 0) ? Wq : Wk, As, Bs, acc, tileM, tileN);
    // fold score scale 1/8 AND log2(e) into Q (exp2-domain softmax downstream)
    const float qs = (z == 0) ? 0.125f * 1.44269504089f : 1.0f;
    unsigned short* C = (z == 0) ? Qp : Kp;
#pragma unroll
    for (int i = 0; i < 4; i++) {
      const size_t row = (size_t)(tileM + wr + i * 16 + l15);
#pragma unroll
      for (int j = 0; j < 4; j++) {
        const int col = tileN + wc + j * 16 + g4 * 4;
        ushort4 pk;
        pk.x = f2bf(acc[j][i][0] * qs); pk.y = f2bf(acc[j][i][1] * qs);
        pk.z = f2bf(acc[j][i][2] * qs); pk.w = f2bf(acc[j][i][3] * qs);
        *reinterpret_cast<ushort4*>(&C[row * 1024 + col]) = pk;
      }
    }
  } else {
    gemm_core<false>(vb, Wv, As, Bs, acc, tileM, tileN);
    // transposed store: VpT[(b*1024 + col)*2048 + s], 4 contiguous s per lane
    const int b = tileM / 2048, s0 = tileM % 2048;
#pragma unroll
    for (int i = 0; i < 4; i++)
#pragma unroll
      for (int j = 0; j < 4; j++) {
        int col = tileN + wc + j * 16 + l15;
        int s = s0 + wr + i * 16 + g4 * 4;
        ushort4 pk;
        pk.x = f2bf(acc[i][j][0]); pk.y = f2bf(acc[i][j][1]);
        pk.z = f2bf(acc[i][j][2]); pk.w = f2bf(acc[i][j][3]);
        *reinterpret_cast<ushort4*>(&VpT[(size_t)(b * 1024 + col) * 2048 + s]) = pk;
      }
  }
}

__global__ __launch_bounds__(256) void gemm_out(
    const unsigned short* __restrict__ Xp, const unsigned short* __restrict__ Wo,
    float* __restrict__ out) {
  __shared__ __align__(16) unsigned short As[128 * 64];
  __shared__ __align__(16) unsigned short Bs[128 * 64];
  const int tileM = blockIdx.x * 128, tileN = blockIdx.y * 128;
  f32x4 acc[4][4];
  gemm_core<true>(Xp, Wo, As, Bs, acc, tileM, tileN);
  const int tid = threadIdx.x, w = tid >> 6, lane = tid & 63;
  const int wr = (w & 1) * 64, wc = (w >> 1) * 64;
  const int l15 = lane & 15, g4 = lane >> 4;
#pragma unroll
  for (int i = 0; i < 4; i++) {
    const size_t row = (size_t)(tileM + wr + i * 16 + l15);
#pragma unroll
    for (int j = 0; j < 4; j++) {
      const int col = tileN + wc + j * 16 + g4 * 4;
      *reinterpret_cast<f32x4*>(&out[row * 1024 + col]) = acc[j][i];
    }
  }
}

// ---- Flash attention, S^T/O^T, no-max softmax, QBLK=256, KBLK=64.
// R13: 2-tile unroll. LDS 80KB (K 4-tile 32 + V 4-tile 32 + Ps 16) ->
// 2 blocks/CU = the grid cap (512 blocks), so no occupancy cost.
// Per iteration (2 tiles): stage(t+2,t+3) -> pair cur^1 ; compute sub-tile
// t (R12 dovetail body) ; compute sub-tile t+1 ; ONE barrier. Loads have
// ~2 compute phases to land -> barrier drain is cheap. launch_bounds(256,2)
// (VGPR cap 256, no spill — R11 lesson). Ps 2-region write-after-read
// reuse is in-wave DS program order (R11/R12-verified).
__global__ __launch_bounds__(256, 2) void attn(
    const unsigned short* __restrict__ Qp, const unsigned short* __restrict__ Kp,
    const unsigned short* __restrict__ VpT, unsigned short* __restrict__ Xp) {
  __shared__ __align__(16) unsigned short Ks[4 * 64 * 64];  // [pair*2+sub][kp][d]
  __shared__ __align__(16) unsigned short Vs[4 * 64 * 64];  // [pair*2+sub][d][kp]
  __shared__ __align__(16) unsigned short Ps[4 * 2 * 1024]; // [wave][2 reg][16x64]

  const int bid = blockIdx.x;
  const int nid = (bid & 7) * 64 + (bid >> 3);  // bijective, 512%8==0
  const int qt = nid & 7, bh = nid >> 3;
  const int b = bh >> 4, h = bh & 15;
  const int q0 = qt * 256;
  const int tid = threadIdx.x, w = tid >> 6, lane = tid & 63;
  const int l15 = lane & 15, g4 = lane >> 4;
  const int l7 = l15 & 7;

  const int rsub = lane >> 3;
  const int gsrc = (lane & 7) ^ rsub;

  // Q rows: wave w owns rows q0 + w*64 + mi*16 + l15
  bf16x8 qf[4][2];
#pragma unroll
  for (int mi = 0; mi < 4; mi++) {
    const unsigned short* Qrow =
        Qp + (size_t)(b * 2048 + q0 + w * 64 + mi * 16 + l15) * 1024 + h * 64;
    qf[mi][0] = *reinterpret_cast<const bf16x8*>(Qrow + g4 * 8);
    qf[mi][1] = *reinterpret_cast<const bf16x8*>(Qrow + 32 + g4 * 8);
  }

  const f32x4 fzero = {0.f, 0.f, 0.f, 0.f};
  f32x4 o[4][4];
#pragma unroll
  for (int mi = 0; mi < 4; mi++)
#pragma unroll
    for (int dj = 0; dj < 4; dj++) o[mi][dj] = fzero;
  float l_i[4] = {0.f, 0.f, 0.f, 0.f};

  const unsigned short* Kbase = Kp + (size_t)(b * 2048) * 1024 + h * 64;
  const unsigned short* Vbase = VpT + (size_t)(b * 1024 + h * 64) * 2048;
  unsigned short* Pw = Ps + w * 2048;  // two 1K-elem regions

  const int c = w * 2;  // this wave's two staging chunks are c, c+1

  // prologue: stage tiles 0,1 into pair 0 (subs 0,1)
#pragma unroll
  for (int s = 0; s < 2; ++s) {
#pragma unroll
    for (int j = 0; j < 2; ++j) {
      ld16(Kbase + (size_t)(s * 64 + (c + j) * 8 + rsub) * 1024 + gsrc * 8,
           Ks + s * 4096 + (c + j) * 512);
      ld16(Vbase + (size_t)((c + j) * 8 + rsub) * 2048 + s * 64 + gsrc * 8,
           Vs + s * 4096 + (c + j) * 512);
    }
  }
  __syncthreads();  // implicit vmcnt(0): tiles 0,1 resident

  int cur = 0;
  for (int t = 0; t < 32; t += 2) {
    // stage tiles t+2, t+3 into the other pair (fly under 2 compute phases)
    if (t < 30) {
#pragma unroll
      for (int s = 0; s < 2; ++s) {
        const int ktn = (t + 2 + s) * 64;
        unsigned short* Kn = Ks + ((cur ^ 1) * 2 + s) * 4096;
        unsigned short* Vn = Vs + ((cur ^ 1) * 2 + s) * 4096;
#pragma unroll
        for (int j = 0; j < 2; ++j) {
          ld16(Kbase + (size_t)(ktn + (c + j) * 8 + rsub) * 1024 + gsrc * 8,
               Kn + (c + j) * 512);
          ld16(Vbase + (size_t)((c + j) * 8 + rsub) * 2048 + ktn + gsrc * 8,
               Vn + (c + j) * 512);
        }
      }
    }

    // compute the two resident sub-tiles (R12 dovetail body each)
#pragma unroll
    for (int s = 0; s < 2; ++s) {
      const unsigned short* Kc = Ks + (cur * 2 + s) * 4096;
      const unsigned short* Vc = Vs + (cur * 2 + s) * 4096;

      // QK: sv[mi][jt][r] = S'[m=mi*16+l15][kp = jt*16 + g4*4 + r]
      f32x4 sv[4][4];
      __builtin_amdgcn_s_setprio(1);
#pragma unroll
      for (int jt = 0; jt < 4; jt++) {
        const int row = jt * 16 + l15;
        const int s0 = g4 ^ l7;
        bf16x8 kf0 = *reinterpret_cast<const bf16x8*>(&Kc[row * 64 + s0 * 8]);
        bf16x8 kf1 = *reinterpret_cast<const bf16x8*>(&Kc[row * 64 + (s0 ^ 4) * 8]);
#pragma unroll
        for (int mi = 0; mi < 4; mi++) {
          f32x4 z = fzero;
          z = __builtin_amdgcn_mfma_f32_16x16x32_bf16(kf0, qf[mi][0], z, 0, 0, 0);
          z = __builtin_amdgcn_mfma_f32_16x16x32_bf16(kf1, qf[mi][1], z, 0, 0, 0);
          sv[mi][jt] = z;
        }
      }
      __builtin_amdgcn_s_setprio(0);

      // exp2+sum+pack m0 -> region 0, m1 -> region 1
#pragma unroll
      for (int mi = 0; mi < 2; mi++) {
        float rs = 0.f;
#pragma unroll
        for (int jt = 0; jt < 4; jt++)
#pragma unroll
          for (int r = 0; r < 4; r++) {
            sv[mi][jt][r] = fexp2(sv[mi][jt][r]);
            rs += sv[mi][jt][r];
          }
        l_i[mi] += rs;
        unsigned short* reg = Pw + mi * 1024;
#pragma unroll
        for (int jt = 0; jt < 4; jt++) {
          u32x2 pk;
          pk.x = pack2bf(sv[mi][jt][0], sv[mi][jt][1]);
          pk.y = pack2bf(sv[mi][jt][2], sv[mi][jt][3]);
          const int slot = (jt * 4 + g4) ^ l15;
          *reinterpret_cast<u32x2*>(&reg[l15 * 64 + slot * 4]) = pk;
        }
      }

      // V fragments: read once, reused for all 4 m-tiles
      bf16x8 vf[2][4];
#pragma unroll
      for (int kc = 0; kc < 2; kc++)
#pragma unroll
        for (int dj = 0; dj < 4; dj++)
          vf[kc][dj] = *reinterpret_cast<const bf16x8*>(
              &Vc[(dj * 16 + l15) * 64 + ((kc * 4 + g4) ^ l7) * 8]);

      // per-mi: read pf(mi) from region mi&1; mi<2 also exp2+pack(mi+2)
      // into the SAME region (write after read: in-wave order safe); PV(mi).
#pragma unroll
      for (int mi = 0; mi < 4; mi++) {
        unsigned short* reg = Pw + (mi & 1) * 1024;
        u32x2 pa[2], pb[2];
#pragma unroll
        for (int kc = 0; kc < 2; kc++) {
          const int sA = (kc * 8 + g4 * 2) ^ l15;
          const int sB = (kc * 8 + g4 * 2 + 1) ^ l15;
          pa[kc] = *reinterpret_cast<const u32x2*>(&reg[l15 * 64 + sA * 4]);
          pb[kc] = *reinterpret_cast<const u32x2*>(&reg[l15 * 64 + sB * 4]);
        }

        if (mi < 2) {
          const int mn = mi + 2;
          float rs = 0.f;
#pragma unroll
          for (int jt = 0; jt < 4; jt++)
#pragma unroll
            for (int r = 0; r < 4; r++) {
              sv[mn][jt][r] = fexp2(sv[mn][jt][r]);
              rs += sv[mn][jt][r];
            }
          l_i[mn] += rs;
#pragma unroll
          for (int jt = 0; jt < 4; jt++) {
            u32x2 pk;
            pk.x = pack2bf(sv[mn][jt][0], sv[mn][jt][1]);
            pk.y = pack2bf(sv[mn][jt][2], sv[mn][jt][3]);
            const int slot = (jt * 4 + g4) ^ l15;
            *reinterpret_cast<u32x2*>(&reg[l15 * 64 + slot * 4]) = pk;
          }
        }

        __builtin_amdgcn_s_setprio(1);
#pragma unroll
        for (int kc = 0; kc < 2; kc++) {
          union { unsigned int u[4]; bf16x8 v; } pf;
          pf.u[0] = pa[kc].x; pf.u[1] = pa[kc].y;
          pf.u[2] = pb[kc].x; pf.u[3] = pb[kc].y;
#pragma unroll
          for (int dj = 0; dj < 4; dj++)
            o[mi][dj] = __builtin_amdgcn_mfma_f32_16x16x32_bf16(vf[kc][dj], pf.v,
                                                               o[mi][dj], 0, 0, 0);
        }
        __builtin_amdgcn_s_setprio(0);
      }
    }

    // ONE barrier per 2 tiles: (a) all waves done reading pair[cur] before
    // it is restaged next iter; (b) implicit vmcnt(0) drains (t+2,t+3)'s
    // loads, in flight across both compute phases above.
    __syncthreads();
    cur ^= 1;
  }

  // epilogue: reduce denominator over the 4 g4 groups, then store O^T
#pragma unroll
  for (int mi = 0; mi < 4; mi++) {
    float rs = l_i[mi];
    rs += __shfl_xor(rs, 16);
    rs += __shfl_xor(rs, 32);
    const float inv = 1.f / rs;
    const size_t row = (size_t)(b * 2048 + q0 + w * 64 + mi * 16 + l15);
#pragma unroll
    for (int dj = 0; dj < 4; dj++) {
      ushort4 pk;
      pk.x = f2bf(o[mi][dj][0] * inv);
      pk.y = f2bf(o[mi][dj][1] * inv);
      pk.z = f2bf(o[mi][dj][2] * inv);
      pk.w = f2bf(o[mi][dj][3] * inv);
      *reinterpret_cast<ushort4*>(&Xp[row * 1024 + h * 64 + dj * 16 + g4 * 4]) = pk;
    }
  }
}

extern "C" void kernel_launch(void* const* d_in, const int* in_sizes, int n_in,
                              void* d_out, int out_size, void* d_ws, size_t ws_size,
                              hipStream_t stream) {
  const float* q  = (const float*)d_in[0];
  const float* k  = (const float*)d_in[1];
  const float* v  = (const float*)d_in[2];
  // d_in[3] mask: unused by the reference
  const float* Wq = (const float*)d_in[4];
  const float* Wk = (const float*)d_in[5];
  const float* Wv = (const float*)d_in[6];
  const float* Wo = (const float*)d_in[7];
  float* out = (float*)d_out;

  char* ws = (char*)d_ws;
  const size_t MB = 1u << 20;
  unsigned short* qb  = (unsigned short*)(ws + 0 * MB);    // 16 MB each
  unsigned short* kb  = (unsigned short*)(ws + 16 * MB);
  unsigned short* vb  = (unsigned short*)(ws + 32 * MB);
  unsigned short* wqb = (unsigned short*)(ws + 48 * MB);   // 2 MB each
  unsigned short* wkb = (unsigned short*)(ws + 50 * MB);
  unsigned short* wvb = (unsigned short*)(ws + 52 * MB);
  unsigned short* wob = (unsigned short*)(ws + 54 * MB);
  unsigned short* Qp  = (unsigned short*)(ws + 56 * MB);   // 16 MB (pre-scaled)
  unsigned short* Kp  = (unsigned short*)(ws + 72 * MB);   // 16 MB
  unsigned short* VpT = (unsigned short*)(ws + 88 * MB);   // 16 MB, [B*1024, 2048]
  unsigned short* Xp  = (unsigned short*)(ws + 104 * MB);  // 16 MB

  // 3*8192 blocks (q,k,v) + 4*1024 blocks (weights) = 28672
  cast_all<<<dim3(28672), 256, 0, stream>>>(q, k, v, Wq, Wk, Wv, Wo,
                                            qb, kb, vb, wqb, wkb, wvb, wob);

  dim3 gq(64, 8, 3);
  gemm_qkv<<<gq, 256, 0, stream>>>(qb, kb, vb, wqb, wkb, wvb, Qp, Kp, VpT);

  attn<<<dim3(512), 256, 0, stream>>>(Qp, Kp, VpT, Xp);

  dim3 go(64, 8, 1);
  gemm_out<<<go, 256, 0, stream>>>(Xp, wob, out);
}

// Round 17
// 335.542 us; speedup vs baseline: 1.1408x; 1.1408x over previous
//
#include <hip/hip_runtime.h>
#include <math.h>

// Problem: B=4, S=2048, D=1024, H=16, DK=64.
// out = softmax((q Wq^T)(k Wk^T)^T / 8) (v Wv^T) Wo^T, heads split on D.
//
// Pipeline:
//   1. cast_all: fp32->bf16 for {q,k,v,Wq,Wk,Wv,Wo} in ONE launch
//   2. gemm_qkv: Qp=(q@Wq^T)*(0.125*log2e), Kp=k@Wk^T (bf16 [8192,1024]),
//                VpT = (v@Wv^T) stored transposed [B*1024, 2048] bf16
//   3. attn: flash attention, S^T/O^T, QBLK=256 (R10 win). R12 (session
//            best, 97.7us attn / 345.3us total): Ps = 2 regions/wave (16KB)
//            -> LDS 48KB, launch_bounds(256,2) (VGPR cap 256, no spill —
//            R11 lesson: (256,4)'s 128-cap spilled o/sv -> 2.4GB scratch).
//            R13's 2-tile unroll REVERTED (spill: VGPR 128 + 127MB
//            WRITE_SIZE -> 132us). mi-dovetail: exp2/pack(mi+2) hides
//            under PV(mi); region write-after-read is in-wave DS order.
//   4. gemm_out: out = Xp @ Wo^T (fp32), BK=64 + C^T epilogue -> float4.

#define DEV __device__ __forceinline__

typedef __bf16 bf16x8 __attribute__((ext_vector_type(8)));
typedef __bf16 bf16x2 __attribute__((ext_vector_type(2)));
typedef float f32x4 __attribute__((ext_vector_type(4)));
typedef unsigned int u32x2 __attribute__((ext_vector_type(2)));

typedef __attribute__((address_space(1))) const unsigned int g_u32;
typedef __attribute__((address_space(3))) unsigned int l_u32;

DEV unsigned short f2bf(float x) {  // RNE truncate to bf16
  unsigned int u = __float_as_uint(x);
  u += 0x7fffu + ((u >> 16) & 1u);
  return (unsigned short)(u >> 16);
}

DEV unsigned int pack2bf(float a, float b) {
#if __has_builtin(__builtin_amdgcn_cvt_pk_bf16_f32)
  bf16x2 r = __builtin_amdgcn_cvt_pk_bf16_f32(a, b);
  union { bf16x2 v; unsigned int u; } c;
  c.v = r;
  return c.u;
#else
  unsigned int ua = __float_as_uint(a) + 0x8000u;
  unsigned int ub = __float_as_uint(b) + 0x8000u;
  return (ua >> 16) | (ub & 0xffff0000u);
#endif
}

DEV float fexp2(float x) {
#if __has_builtin(__builtin_amdgcn_exp2f)
  return __builtin_amdgcn_exp2f(x);
#else
  return __expf(x * 0.69314718056f);
#endif
}

DEV void ld16(const unsigned short* g, unsigned short* l) {
  // async global->LDS, 16B per lane; LDS dest = wave-uniform base + lane*16
  __builtin_amdgcn_global_load_lds((g_u32*)g, (l_u32*)l, 16, 0, 0);
}

// One launch for all 7 casts. Blocks 0..24575: q,k,v (8192 blocks each,
// 2M float4 per tensor). Blocks 24576..28671: weights (1024 blocks each).
__global__ __launch_bounds__(256) void cast_all(
    const float* __restrict__ q, const float* __restrict__ k,
    const float* __restrict__ v, const float* __restrict__ w0,
    const float* __restrict__ w1, const float* __restrict__ w2,
    const float* __restrict__ w3, unsigned short* __restrict__ qb,
    unsigned short* __restrict__ kb, unsigned short* __restrict__ vb,
    unsigned short* __restrict__ o0, unsigned short* __restrict__ o1,
    unsigned short* __restrict__ o2, unsigned short* __restrict__ o3) {
  const int bb = blockIdx.x;
  const float* src;
  unsigned short* dst;
  int i;
  if (bb < 24576) {
    const int z = bb >> 13, lb = bb & 8191;
    src = (z == 0) ? q : (z == 1) ? k : v;
    dst = (z == 0) ? qb : (z == 1) ? kb : vb;
    i = lb * 256 + threadIdx.x;
  } else {
    const int t = bb - 24576;
    const int z = t >> 10, lb = t & 1023;
    src = (z == 0) ? w0 : (z == 1) ? w1 : (z == 2) ? w2 : w3;
    dst = (z == 0) ? o0 : (z == 1) ? o1 : (z == 2) ? o2 : o3;
    i = lb * 256 + threadIdx.x;
  }
  float4 vv = reinterpret_cast<const float4*>(src)[i];
  ushort4 o;
  o.x = f2bf(vv.x); o.y = f2bf(vv.y); o.z = f2bf(vv.z); o.w = f2bf(vv.w);
  reinterpret_cast<ushort4*>(dst)[i] = o;
}

// ---- NT GEMM core, BK=64: C[128x128] tile, A [M,1024] bf16 rm, W [N,1024].
// 4 waves, each 64x64 (4x4 MFMA tiles of 16x16x32 bf16). 32 MFMA per barrier
// pair. LDS tiles 128x64 (row stride 128B) with XOR granule swizzle
// (phys_granule = logical ^ (row&7)) -> conflict-free b128 reads.
// SW=true computes C^T (mfma(bF,aF)) -> acc[j][i], lane holds 4 consecutive
// output cols of one row; SW=false computes C -> acc[i][j] (m97 layout).
template <bool SW>
DEV void gemm_core(const unsigned short* __restrict__ A,
                   const unsigned short* __restrict__ W,
                   unsigned short* As, unsigned short* Bs,
                   f32x4 (&acc)[4][4], int tileM, int tileN) {
  const int tid = threadIdx.x;
  const int w = tid >> 6, lane = tid & 63;
  const int wr = (w & 1) * 64, wc = (w >> 1) * 64;
  const int l15 = lane & 15, g4 = lane >> 4, l7 = l15 & 7;
  const int rsub = lane >> 3;            // row within 8-row staging chunk
  const int gsrc = (lane & 7) ^ rsub;    // swizzled source granule (8 shorts)

  const f32x4 fzero = {0.f, 0.f, 0.f, 0.f};
#pragma unroll
  for (int i = 0; i < 4; i++)
#pragma unroll
    for (int j = 0; j < 4; j++) acc[i][j] = fzero;

  for (int k0 = 0; k0 < 1024; k0 += 64) {
#pragma unroll
    for (int j = 0; j < 4; ++j) {
      const int c = w * 4 + j;  // chunk: 8 rows x 128B = 1KB
      ld16(A + (size_t)(tileM + c * 8 + rsub) * 1024 + k0 + gsrc * 8, As + c * 512);
      ld16(W + (size_t)(tileN + c * 8 + rsub) * 1024 + k0 + gsrc * 8, Bs + c * 512);
    }
    __syncthreads();
#pragma unroll
    for (int kc = 0; kc < 2; kc++) {
      const int ph = ((kc * 4 + g4) ^ l7) * 8;
      bf16x8 aF[4], bF[4];
#pragma unroll
      for (int i = 0; i < 4; i++)
        aF[i] = *reinterpret_cast<const bf16x8*>(&As[(wr + i * 16 + l15) * 64 + ph]);
#pragma unroll
      for (int j = 0; j < 4; j++)
        bF[j] = *reinterpret_cast<const bf16x8*>(&Bs[(wc + j * 16 + l15) * 64 + ph]);
#pragma unroll
      for (int i = 0; i < 4; i++)
#pragma unroll
        for (int j = 0; j < 4; j++) {
          if (SW)
            acc[j][i] = __builtin_amdgcn_mfma_f32_16x16x32_bf16(bF[j], aF[i], acc[j][i], 0, 0, 0);
          else
            acc[i][j] = __builtin_amdgcn_mfma_f32_16x16x32_bf16(aF[i], bF[j], acc[i][j], 0, 0, 0);
        }
    }
    __syncthreads();
  }
}

__global__ __launch_bounds__(256) void gemm_qkv(
    const unsigned short* __restrict__ qb, const unsigned short* __restrict__ kb,
    const unsigned short* __restrict__ vb, const unsigned short* __restrict__ Wq,
    const unsigned short* __restrict__ Wk, const unsigned short* __restrict__ Wv,
    unsigned short* __restrict__ Qp, unsigned short* __restrict__ Kp,
    unsigned short* __restrict__ VpT) {
  __shared__ __align__(16) unsigned short As[128 * 64];
  __shared__ __align__(16) unsigned short Bs[128 * 64];
  const int z = blockIdx.z;
  const int tileM = blockIdx.x * 128, tileN = blockIdx.y * 128;
  const int tid = threadIdx.x, w = tid >> 6, lane = tid & 63;
  const int wr = (w & 1) * 64, wc = (w >> 1) * 64;
  const int l15 = lane & 15, g4 = lane >> 4;
  f32x4 acc[4][4];

  if (z < 2) {
    // C^T core: lane holds row tileM+wr+i*16+l15, cols +wc+j*16+g4*4+(0..3)
    gemm_core<true>((z == 0) ? qb : kb, (z == 0) ? Wq : Wk, As, Bs, acc, tileM, tileN);
    // fold score scale 1/8 AND log2(e) into Q (exp2-domain softmax downstream)
    const float qs = (z == 0) ? 0.125f * 1.44269504089f : 1.0f;
    unsigned short* C = (z == 0) ? Qp : Kp;
#pragma unroll
    for (int i = 0; i < 4; i++) {
      const size_t row = (size_t)(tileM + wr + i * 16 + l15);
#pragma unroll
      for (int j = 0; j < 4; j++) {
        const int col = tileN + wc + j * 16 + g4 * 4;
        ushort4 pk;
        pk.x = f2bf(acc[j][i][0] * qs); pk.y = f2bf(acc[j][i][1] * qs);
        pk.z = f2bf(acc[j][i][2] * qs); pk.w = f2bf(acc[j][i][3] * qs);
        *reinterpret_cast<ushort4*>(&C[row * 1024 + col]) = pk;
      }
    }
  } else {
    gemm_core<false>(vb, Wv, As, Bs, acc, tileM, tileN);
    // transposed store: VpT[(b*1024 + col)*2048 + s], 4 contiguous s per lane
    const int b = tileM / 2048, s0 = tileM % 2048;
#pragma unroll
    for (int i = 0; i < 4; i++)
#pragma unroll
      for (int j = 0; j < 4; j++) {
        int col = tileN + wc + j * 16 + l15;
        int s = s0 + wr + i * 16 + g4 * 4;
        ushort4 pk;
        pk.x = f2bf(acc[i][j][0]); pk.y = f2bf(acc[i][j][1]);
        pk.z = f2bf(acc[i][j][2]); pk.w = f2bf(acc[i][j][3]);
        *reinterpret_cast<ushort4*>(&VpT[(size_t)(b * 1024 + col) * 2048 + s]) = pk;
      }
  }
}

__global__ __launch_bounds__(256) void gemm_out(
    const unsigned short* __restrict__ Xp, const unsigned short* __restrict__ Wo,
    float* __restrict__ out) {
  __shared__ __align__(16) unsigned short As[128 * 64];
  __shared__ __align__(16) unsigned short Bs[128 * 64];
  const int tileM = blockIdx.x * 128, tileN = blockIdx.y * 128;
  f32x4 acc[4][4];
  gemm_core<true>(Xp, Wo, As, Bs, acc, tileM, tileN);
  const int tid = threadIdx.x, w = tid >> 6, lane = tid & 63;
  const int wr = (w & 1) * 64, wc = (w >> 1) * 64;
  const int l15 = lane & 15, g4 = lane >> 4;
#pragma unroll
  for (int i = 0; i < 4; i++) {
    const size_t row = (size_t)(tileM + wr + i * 16 + l15);
#pragma unroll
    for (int j = 0; j < 4; j++) {
      const int col = tileN + wc + j * 16 + g4 * 4;
      *reinterpret_cast<f32x4*>(&out[row * 1024 + col]) = acc[j][i];
    }
  }
}

// ---- Flash attention, S^T/O^T, no-max softmax, QBLK=256, KBLK=64.
// R12 (session best): LDS 48KB (K dbuf 16 + V dbuf 16 + Ps 16).
// launch_bounds(256,2): VGPR cap 256, no spill (VGPR 124 measured).
// Ps: 2 regions/wave; mi uses region mi&1; pack(mi+2) is issued AFTER
// read(mi) of the same region (in-wave DS program order -> safe). Per tile:
//   stage(t+1) ; QK(all mi) ; exp2+pack(m0->r0, m1->r1) ; vf ;
//   mi=0: read r0, exp2+pack(m2->r0), PV(0)
//   mi=1: read r1, exp2+pack(m3->r1), PV(1)
//   mi=2: read r0, PV(2) ; mi=3: read r1, PV(3) ; ONE barrier.
__global__ __launch_bounds__(256, 2) void attn(
    const unsigned short* __restrict__ Qp, const unsigned short* __restrict__ Kp,
    const unsigned short* __restrict__ VpT, unsigned short* __restrict__ Xp) {
  __shared__ __align__(16) unsigned short Ks[2 * 64 * 64];  // [buf][kp][d]
  __shared__ __align__(16) unsigned short Vs[2 * 64 * 64];  // [buf][d][kp]
  __shared__ __align__(16) unsigned short Ps[4 * 2 * 1024]; // [wave][2 reg][16x64]

  const int bid = blockIdx.x;
  const int nid = (bid & 7) * 64 + (bid >> 3);  // bijective, 512%8==0
  const int qt = nid & 7, bh = nid >> 3;
  const int b = bh >> 4, h = bh & 15;
  const int q0 = qt * 256;
  const int tid = threadIdx.x, w = tid >> 6, lane = tid & 63;
  const int l15 = lane & 15, g4 = lane >> 4;
  const int l7 = l15 & 7;

  const int rsub = lane >> 3;
  const int gsrc = (lane & 7) ^ rsub;

  // Q rows: wave w owns rows q0 + w*64 + mi*16 + l15
  bf16x8 qf[4][2];
#pragma unroll
  for (int mi = 0; mi < 4; mi++) {
    const unsigned short* Qrow =
        Qp + (size_t)(b * 2048 + q0 + w * 64 + mi * 16 + l15) * 1024 + h * 64;
    qf[mi][0] = *reinterpret_cast<const bf16x8*>(Qrow + g4 * 8);
    qf[mi][1] = *reinterpret_cast<const bf16x8*>(Qrow + 32 + g4 * 8);
  }

  const f32x4 fzero = {0.f, 0.f, 0.f, 0.f};
  f32x4 o[4][4];
#pragma unroll
  for (int mi = 0; mi < 4; mi++)
#pragma unroll
    for (int dj = 0; dj < 4; dj++) o[mi][dj] = fzero;
  float l_i[4] = {0.f, 0.f, 0.f, 0.f};

  const unsigned short* Kbase = Kp + (size_t)(b * 2048) * 1024 + h * 64;
  const unsigned short* Vbase = VpT + (size_t)(b * 1024 + h * 64) * 2048;
  unsigned short* Pw = Ps + w * 2048;  // two 1K-elem regions

  const int c = w * 2;  // this wave's two staging chunks are c, c+1

  // prologue: stage tile 0 into buffer 0
#pragma unroll
  for (int j = 0; j < 2; ++j) {
    ld16(Kbase + (size_t)((c + j) * 8 + rsub) * 1024 + gsrc * 8, Ks + (c + j) * 512);
    ld16(Vbase + (size_t)((c + j) * 8 + rsub) * 2048 + gsrc * 8, Vs + (c + j) * 512);
  }
  __syncthreads();  // implicit vmcnt(0): tile 0 resident

  int cur = 0;
  for (int t = 0; t < 32; ++t) {
    const int kt = t * 64;
    unsigned short* Kc = Ks + cur * 4096;
    unsigned short* Vc = Vs + cur * 4096;

    // stage tile t+1 into the other buffer (flies under this tile's compute)
    if (t < 31) {
      unsigned short* Kn = Ks + (cur ^ 1) * 4096;
      unsigned short* Vn = Vs + (cur ^ 1) * 4096;
      const int ktn = kt + 64;
#pragma unroll
      for (int j = 0; j < 2; ++j) {
        ld16(Kbase + (size_t)(ktn + (c + j) * 8 + rsub) * 1024 + gsrc * 8,
             Kn + (c + j) * 512);
        ld16(Vbase + (size_t)((c + j) * 8 + rsub) * 2048 + ktn + gsrc * 8,
             Vn + (c + j) * 512);
      }
    }

    // QK: sv[mi][jt][r] = S'[m=mi*16+l15][kp = kt + jt*16 + g4*4 + r]
    f32x4 sv[4][4];
    __builtin_amdgcn_s_setprio(1);
#pragma unroll
    for (int jt = 0; jt < 4; jt++) {
      const int row = jt * 16 + l15;
      const int s0 = g4 ^ l7;
      bf16x8 kf0 = *reinterpret_cast<const bf16x8*>(&Kc[row * 64 + s0 * 8]);
      bf16x8 kf1 = *reinterpret_cast<const bf16x8*>(&Kc[row * 64 + (s0 ^ 4) * 8]);
#pragma unroll
      for (int mi = 0; mi < 4; mi++) {
        f32x4 z = fzero;
        z = __builtin_amdgcn_mfma_f32_16x16x32_bf16(kf0, qf[mi][0], z, 0, 0, 0);
        z = __builtin_amdgcn_mfma_f32_16x16x32_bf16(kf1, qf[mi][1], z, 0, 0, 0);
        sv[mi][jt] = z;
      }
    }
    __builtin_amdgcn_s_setprio(0);

    // exp2+sum+pack m0 -> region 0, m1 -> region 1
#pragma unroll
    for (int mi = 0; mi < 2; mi++) {
      float rs = 0.f;
#pragma unroll
      for (int jt = 0; jt < 4; jt++)
#pragma unroll
        for (int r = 0; r < 4; r++) {
          sv[mi][jt][r] = fexp2(sv[mi][jt][r]);
          rs += sv[mi][jt][r];
        }
      l_i[mi] += rs;
      unsigned short* reg = Pw + mi * 1024;
#pragma unroll
      for (int jt = 0; jt < 4; jt++) {
        u32x2 pk;
        pk.x = pack2bf(sv[mi][jt][0], sv[mi][jt][1]);
        pk.y = pack2bf(sv[mi][jt][2], sv[mi][jt][3]);
        const int slot = (jt * 4 + g4) ^ l15;
        *reinterpret_cast<u32x2*>(&reg[l15 * 64 + slot * 4]) = pk;
      }
    }

    // V fragments: read once, reused for all 4 m-tiles
    bf16x8 vf[2][4];
#pragma unroll
    for (int kc = 0; kc < 2; kc++)
#pragma unroll
      for (int dj = 0; dj < 4; dj++)
        vf[kc][dj] = *reinterpret_cast<const bf16x8*>(
            &Vc[(dj * 16 + l15) * 64 + ((kc * 4 + g4) ^ l7) * 8]);

    // per-mi: read pf(mi) from region mi&1; for mi<2 also exp2+pack(mi+2)
    // into the SAME region (write issued after read: in-wave order safe);
    // then PV(mi).
#pragma unroll
    for (int mi = 0; mi < 4; mi++) {
      unsigned short* reg = Pw + (mi & 1) * 1024;
      u32x2 pa[2], pb[2];
#pragma unroll
      for (int kc = 0; kc < 2; kc++) {
        const int sA = (kc * 8 + g4 * 2) ^ l15;
        const int sB = (kc * 8 + g4 * 2 + 1) ^ l15;
        pa[kc] = *reinterpret_cast<const u32x2*>(&reg[l15 * 64 + sA * 4]);
        pb[kc] = *reinterpret_cast<const u32x2*>(&reg[l15 * 64 + sB * 4]);
      }

      if (mi < 2) {
        const int mn = mi + 2;
        float rs = 0.f;
#pragma unroll
        for (int jt = 0; jt < 4; jt++)
#pragma unroll
          for (int r = 0; r < 4; r++) {
            sv[mn][jt][r] = fexp2(sv[mn][jt][r]);
            rs += sv[mn][jt][r];
          }
        l_i[mn] += rs;
#pragma unroll
        for (int jt = 0; jt < 4; jt++) {
          u32x2 pk;
          pk.x = pack2bf(sv[mn][jt][0], sv[mn][jt][1]);
          pk.y = pack2bf(sv[mn][jt][2], sv[mn][jt][3]);
          const int slot = (jt * 4 + g4) ^ l15;
          *reinterpret_cast<u32x2*>(&reg[l15 * 64 + slot * 4]) = pk;
        }
      }

      __builtin_amdgcn_s_setprio(1);
#pragma unroll
      for (int kc = 0; kc < 2; kc++) {
        union { unsigned int u[4]; bf16x8 v; } pf;
        pf.u[0] = pa[kc].x; pf.u[1] = pa[kc].y;
        pf.u[2] = pb[kc].x; pf.u[3] = pb[kc].y;
#pragma unroll
        for (int dj = 0; dj < 4; dj++)
          o[mi][dj] = __builtin_amdgcn_mfma_f32_16x16x32_bf16(vf[kc][dj], pf.v,
                                                             o[mi][dj], 0, 0, 0);
      }
      __builtin_amdgcn_s_setprio(0);
    }

    // ONE barrier per tile: (a) all waves done reading buf[cur] before it is
    // restaged next iter; (b) implicit vmcnt(0) drains t+1's loads, which
    // have been in flight across the whole compute phase above.
    __syncthreads();
    cur ^= 1;
  }

  // epilogue: reduce denominator over the 4 g4 groups, then store O^T
#pragma unroll
  for (int mi = 0; mi < 4; mi++) {
    float rs = l_i[mi];
    rs += __shfl_xor(rs, 16);
    rs += __shfl_xor(rs, 32);
    const float inv = 1.f / rs;
    const size_t row = (size_t)(b * 2048 + q0 + w * 64 + mi * 16 + l15);
#pragma unroll
    for (int dj = 0; dj < 4; dj++) {
      ushort4 pk;
      pk.x = f2bf(o[mi][dj][0] * inv);
      pk.y = f2bf(o[mi][dj][1] * inv);
      pk.z = f2bf(o[mi][dj][2] * inv);
      pk.w = f2bf(o[mi][dj][3] * inv);
      *reinterpret_cast<ushort4*>(&Xp[row * 1024 + h * 64 + dj * 16 + g4 * 4]) = pk;
    }
  }
}

extern "C" void kernel_launch(void* const* d_in, const int* in_sizes, int n_in,
                              void* d_out, int out_size, void* d_ws, size_t ws_size,
                              hipStream_t stream) {
  const float* q  = (const float*)d_in[0];
  const float* k  = (const float*)d_in[1];
  const float* v  = (const float*)d_in[2];
  // d_in[3] mask: unused by the reference
  const float* Wq = (const float*)d_in[4];
  const float* Wk = (const float*)d_in[5];
  const float* Wv = (const float*)d_in[6];
  const float* Wo = (const float*)d_in[7];
  float* out = (float*)d_out;

  char* ws = (char*)d_ws;
  const size_t MB = 1u << 20;
  unsigned short* qb  = (unsigned short*)(ws + 0 * MB);    // 16 MB each
  unsigned short* kb  = (unsigned short*)(ws + 16 * MB);
  unsigned short* vb  = (unsigned short*)(ws + 32 * MB);
  unsigned short* wqb = (unsigned short*)(ws + 48 * MB);   // 2 MB each
  unsigned short* wkb = (unsigned short*)(ws + 50 * MB);
  unsigned short* wvb = (unsigned short*)(ws + 52 * MB);
  unsigned short* wob = (unsigned short*)(ws + 54 * MB);
  unsigned short* Qp  = (unsigned short*)(ws + 56 * MB);   // 16 MB (pre-scaled)
  unsigned short* Kp  = (unsigned short*)(ws + 72 * MB);   // 16 MB
  unsigned short* VpT = (unsigned short*)(ws + 88 * MB);   // 16 MB, [B*1024, 2048]
  unsigned short* Xp  = (unsigned short*)(ws + 104 * MB);  // 16 MB

  // 3*8192 blocks (q,k,v) + 4*1024 blocks (weights) = 28672
  cast_all<<<dim3(28672), 256, 0, stream>>>(q, k, v, Wq, Wk, Wv, Wo,
                                            qb, kb, vb, wqb, wkb, wvb, wob);

  dim3 gq(64, 8, 3);
  gemm_qkv<<<gq, 256, 0, stream>>>(qb, kb, vb, wqb, wkb, wvb, Qp, Kp, VpT);

  attn<<<dim3(512), 256, 0, stream>>>(Qp, Kp, VpT, Xp);

  dim3 go(64, 8, 1);
  gemm_out<<<go, 256, 0, stream>>>(Xp, wob, out);
}